// Round 6
// baseline (379.473 us; speedup 1.0000x reference)
//
#include <hip/hip_runtime.h>

typedef unsigned short u16;
typedef unsigned int u32;
typedef __bf16 bf16x8 __attribute__((ext_vector_type(8)));
typedef float f32x4 __attribute__((ext_vector_type(4)));

__device__ __forceinline__ u16 f2b(float f) {
  u32 u = __float_as_uint(f);
  u32 r = (u + 0x7fffu + ((u >> 16) & 1u)) >> 16;
  return (u16)r;
}
__device__ __forceinline__ float b2f(u16 v) {
  return __uint_as_float(((u32)v) << 16);
}

// ------- fused fp32 -> bf16 cast of query, W_qkv, W_out  (+ RoPE table) -------
__global__ __launch_bounds__(256) void convert_all(
    const float4* __restrict__ q, const float4* __restrict__ w1,
    const float4* __restrict__ w2, ushort4* __restrict__ out,
    float2* __restrict__ tab) {
  int i = blockIdx.x * 256 + threadIdx.x;  // < 6291456
  float4 f;
  if (i < 2097152) f = q[i];
  else if (i < 5242880) f = w1[i - 2097152];
  else f = w2[i - 5242880];
  ushort4 o;
  o.x = f2b(f.x); o.y = f2b(f.y); o.z = f2b(f.z); o.w = f2b(f.w);
  out[i] = o;
  // first 512 blocks also build the RoPE cos/sin table (131072 entries)
  if (blockIdx.x < 512) {
    int l = i >> 6, dp = i & 63;
    float inv = exp2f(-(float)dp * 0.20762050593046869f);  // log2(10000)/64
    float ang = (float)l * inv;
    float s, c;
    sincosf(ang, &s, &c);
    tab[i] = make_float2(c, s);
  }
}

// ---------------- GEMM1 + fused RoPE/head-split/V-transpose epilogue ----------
// Known-good structure (141 us, 730 TF): 128x128 tile, 4 blocks/CU TLP.
__global__ __launch_bounds__(256) void gemm_qkv(
    const u16* __restrict__ A, const u16* __restrict__ B,
    const float* __restrict__ bias, const float2* __restrict__ tab,
    u16* __restrict__ qh, u16* __restrict__ kh, u16* __restrict__ vhT) {
  __shared__ __align__(16) u16 sh[16512];  // As(8192) | Bs(8192); epi: T stride 129
  u16* As = sh;
  u16* Bs = sh + 8192;
  const int K = 2048;
  const int tid = threadIdx.x;
  const int lane = tid & 63;
  const int wave = tid >> 6;
  const int m0 = blockIdx.y * 128;
  const int n0 = blockIdx.x * 128;
  const int wm = (wave & 1) * 64;
  const int wn = (wave >> 1) * 64;
  f32x4 acc[4][4] = {};

  const int srow = wave * 32 + (lane >> 3);
  const int scb = ((lane & 7) ^ (lane >> 3)) * 16;
  const int fr = lane & 15;
  const int g = lane >> 4;

  for (int kt = 0; kt < 32; ++kt) {
    const int k0 = kt << 6;
    __syncthreads();
    {
      const char* gA = (const char*)A + ((size_t)(m0 + srow) * K + k0) * 2 + scb;
      const char* gB = (const char*)B + ((size_t)(n0 + srow) * K + k0) * 2 + scb;
#pragma unroll
      for (int i = 0; i < 4; ++i) {
        __builtin_amdgcn_global_load_lds(
            (__attribute__((address_space(1))) void*)(gA + (size_t)i * 8 * K * 2),
            (__attribute__((address_space(3))) void*)(As + (wave * 32 + i * 8) * 64),
            16, 0, 0);
        __builtin_amdgcn_global_load_lds(
            (__attribute__((address_space(1))) void*)(gB + (size_t)i * 8 * K * 2),
            (__attribute__((address_space(3))) void*)(Bs + (wave * 32 + i * 8) * 64),
            16, 0, 0);
      }
    }
    __syncthreads();
#pragma unroll
    for (int ks = 0; ks < 2; ++ks) {
      const int so = ((ks * 4 + g) ^ (fr & 7)) * 8;
      bf16x8 aF[4], bF[4];
#pragma unroll
      for (int mi = 0; mi < 4; ++mi)
        __builtin_memcpy(&aF[mi], &As[(wm + mi * 16 + fr) * 64 + so], 16);
#pragma unroll
      for (int ni = 0; ni < 4; ++ni)
        __builtin_memcpy(&bF[ni], &Bs[(wn + ni * 16 + fr) * 64 + so], 16);
#pragma unroll
      for (int mi = 0; mi < 4; ++mi)
#pragma unroll
        for (int ni = 0; ni < 4; ++ni)
          acc[mi][ni] = __builtin_amdgcn_mfma_f32_16x16x32_bf16(aF[mi], bF[ni], acc[mi][ni], 0, 0, 0);
    }
  }

  // ---- epilogue: acc -> LDS tile T (bf16, stride 129) ----
  __syncthreads();  // all waves done reading As/Bs before overwrite
  const int rq = (lane >> 4) * 4;
  const int cq = lane & 15;
#pragma unroll
  for (int mi = 0; mi < 4; ++mi) {
#pragma unroll
    for (int ni = 0; ni < 4; ++ni) {
      int c = wn + ni * 16 + cq;
      float bs = bias[n0 + c];
#pragma unroll
      for (int i = 0; i < 4; ++i) {
        int r = wm + mi * 16 + rq + i;
        sh[r * 129 + c] = f2b(acc[mi][ni][i] + bs);
      }
    }
  }
  __syncthreads();

  const int t = n0 >> 7;       // 0..47
  const int h = t & 15;
  const int bq = m0 >> 11;     // batch (M = B*L, 2048 each)
  const int l0 = m0 & 2047;
  const int bh = bq * 16 + h;

  if (t < 32) {
    // q or k head tile: RoPE rows. 128 rows x 64 pairs, 32 iters.
    const float qs = (t < 16) ? 0.08838834764831845f : 1.0f;
    u16* dst = (t < 16) ? qh : kh;
#pragma unroll 4
    for (int it = 0; it < 32; ++it) {
      int idx = it * 256 + tid;
      int l = idx >> 6, dp = idx & 63;
      float2 cs = tab[(size_t)(l0 + l) * 64 + dp];
      float x1 = b2f(sh[l * 129 + dp]);
      float x2 = b2f(sh[l * 129 + dp + 64]);
      size_t o = ((size_t)bh * 2048 + l0 + l) * 128;
      dst[o + dp]      = f2b((x1 * cs.x - x2 * cs.y) * qs);
      dst[o + dp + 64] = f2b((x2 * cs.x + x1 * cs.y) * qs);
    }
  } else {
    // v head tile: transposed store vhT[bh*128+d][l]. 128 d x 64 l-pairs.
#pragma unroll 4
    for (int it = 0; it < 32; ++it) {
      int idx = it * 256 + tid;
      int d = idx >> 6, l2 = (idx & 63) * 2;
      ushort2 t2;
      t2.x = sh[l2 * 129 + d];
      t2.y = sh[(l2 + 1) * 129 + d];
      *(ushort2*)(vhT + ((size_t)bh * 128 + d) * 2048 + l0 + l2) = t2;
    }
  }
}

// ---------------- GEMM2: out[M,N] = A[M,K] * B[N,K]^T + bias (fp32 out) -------
__global__ __launch_bounds__(256) void gemm_bt(
    const u16* __restrict__ A, const u16* __restrict__ B,
    const float* __restrict__ bias, float* __restrict__ C,
    int M, int N, int K) {
  __shared__ __align__(16) u16 As[128 * 64];
  __shared__ __align__(16) u16 Bs[128 * 64];
  const int tid = threadIdx.x;
  const int lane = tid & 63;
  const int wave = tid >> 6;
  const int m0 = blockIdx.y * 128;
  const int n0 = blockIdx.x * 128;
  const int wm = (wave & 1) * 64;
  const int wn = (wave >> 1) * 64;
  f32x4 acc[4][4] = {};

  const int srow = wave * 32 + (lane >> 3);
  const int scb = ((lane & 7) ^ (lane >> 3)) * 16;
  const int fr = lane & 15;
  const int g = lane >> 4;

  const int kiters = K >> 6;
  for (int kt = 0; kt < kiters; ++kt) {
    const int k0 = kt << 6;
    __syncthreads();
    {
      const char* gA = (const char*)A + ((size_t)(m0 + srow) * K + k0) * 2 + scb;
      const char* gB = (const char*)B + ((size_t)(n0 + srow) * K + k0) * 2 + scb;
#pragma unroll
      for (int i = 0; i < 4; ++i) {
        __builtin_amdgcn_global_load_lds(
            (__attribute__((address_space(1))) void*)(gA + (size_t)i * 8 * K * 2),
            (__attribute__((address_space(3))) void*)(As + (wave * 32 + i * 8) * 64),
            16, 0, 0);
        __builtin_amdgcn_global_load_lds(
            (__attribute__((address_space(1))) void*)(gB + (size_t)i * 8 * K * 2),
            (__attribute__((address_space(3))) void*)(Bs + (wave * 32 + i * 8) * 64),
            16, 0, 0);
      }
    }
    __syncthreads();
#pragma unroll
    for (int ks = 0; ks < 2; ++ks) {
      const int so = ((ks * 4 + g) ^ (fr & 7)) * 8;
      bf16x8 aF[4], bF[4];
#pragma unroll
      for (int mi = 0; mi < 4; ++mi)
        __builtin_memcpy(&aF[mi], &As[(wm + mi * 16 + fr) * 64 + so], 16);
#pragma unroll
      for (int ni = 0; ni < 4; ++ni)
        __builtin_memcpy(&bF[ni], &Bs[(wn + ni * 16 + fr) * 64 + so], 16);
#pragma unroll
      for (int mi = 0; mi < 4; ++mi)
#pragma unroll
        for (int ni = 0; ni < 4; ++ni)
          acc[mi][ni] = __builtin_amdgcn_mfma_f32_16x16x32_bf16(aF[mi], bF[ni], acc[mi][ni], 0, 0, 0);
    }
  }
  const int rq = (lane >> 4) * 4;
  const int cq = lane & 15;
#pragma unroll
  for (int mi = 0; mi < 4; ++mi) {
#pragma unroll
    for (int ni = 0; ni < 4; ++ni) {
      int col = n0 + wn + ni * 16 + cq;
      float bs = bias[col];
#pragma unroll
      for (int i = 0; i < 4; ++i) {
        int row = m0 + wm + mi * 16 + rq + i;
        C[(size_t)row * N + col] = acc[mi][ni][i] + bs;
      }
    }
  }
}

// ---------------- causal flash attention, S^T orientation ----------------
// Restructured for concurrency: ONE 64-row q-slice per block, grid 1024.
//   bid = seg*32 + head; sl = 31-seg -> longest slices dispatch first (LPT);
//   head = bid&31 keeps bid%8 == head%8 -> each head's K/V on one XCD L2.
// LDS = Ks(16K) + Vt(16K) + Ps(8K) = 40960 B exactly -> 4 blocks/CU (was
// grid-limited to 2). Ps is [64 rows][8 chunks of 8 u16] with chunk-XOR
// swizzle (chunk ^= row&7; row&7==cq&7) replacing the old +8 pad: write
// ushort4 at ((mt*2+(g>>1))^(cq&7))*8+(g&1)*4, read b128 at ((ks*4+g)^(cq&7))*8.
// Staging: K+V DMA per tile; vmcnt(4) (K landed, V in flight) before QK,
// vmcnt(0) before PV (V latency hides under QK+softmax).
__global__ __launch_bounds__(256, 4) void attn_flash(
    const u16* __restrict__ qh, const u16* __restrict__ kh,
    const u16* __restrict__ vhT, u16* __restrict__ oh) {
  __shared__ __align__(16) u16 Ks[64 * 128];   // 16 KB
  __shared__ __align__(16) u16 Vt[128 * 64];   // 16 KB
  __shared__ __align__(16) u16 Ps[64 * 64];    //  8 KB (chunk-swizzled)
  const int tid = threadIdx.x;
  const int lane = tid & 63;
  const int w = tid >> 6;
  const int cq = lane & 15;
  const int g = lane >> 4;
  const int bid = blockIdx.x;          // 0..1023
  const int bh = bid & 31;             // head; bh%8 == bid%8 (XCD cluster)
  const int sl = 31 - (bid >> 5);      // q-slice; longest first
  const int b = bh >> 4, h = bh & 15;
  const int q0 = sl * 64;
  const int qg = q0 + w * 16 + cq;     // this lane's q row

  const int krl = lane >> 4;
  const int kcl = lane & 15;
  const int vrl = lane >> 3;
  const int vcl = lane & 7;

  // Q fragments (4 x 16B global loads)
  bf16x8 qf[4];
  {
    const u16* qp = qh + ((size_t)bh * 2048 + qg) * 128 + g * 8;
#pragma unroll
    for (int ks = 0; ks < 4; ++ks)
      __builtin_memcpy(&qf[ks], qp + ks * 32, 16);
  }

  f32x4 o[8] = {};
  float mrow = -1e30f, lrow = 0.0f;

  for (int kt = 0; kt <= sl; ++kt) {
    // prev-iter Ks/Vt reads complete before DMA overwrite (no vm drain needed)
    __builtin_amdgcn_s_barrier();
    __builtin_amdgcn_sched_barrier(0);
    {
      const size_t kvb = (size_t)bh * 2048 + (size_t)kt * 64;
#pragma unroll
      for (int i = 0; i < 4; ++i) {
        int row = w * 16 + i * 4 + krl;
        int cgl = kcl ^ (row & 7);
        const char* src = (const char*)(kh + (kvb + row) * 128 + cgl * 8);
        __builtin_amdgcn_global_load_lds(
            (__attribute__((address_space(1))) void*)src,
            (__attribute__((address_space(3))) void*)(Ks + (w * 16 + i * 4) * 128),
            16, 0, 0);
      }
#pragma unroll
      for (int i = 0; i < 4; ++i) {
        int row = w * 32 + i * 8 + vrl;
        int cgl = vcl ^ (row & 7);
        const char* src =
            (const char*)(vhT + ((size_t)bh * 128 + row) * 2048 + kt * 64 + cgl * 8);
        __builtin_amdgcn_global_load_lds(
            (__attribute__((address_space(1))) void*)src,
            (__attribute__((address_space(3))) void*)(Vt + (w * 32 + i * 8) * 64),
            16, 0, 0);
      }
    }
    // K's 4 loads landed (V's 4 newest still in flight); iter 0 also drains Q
    asm volatile("s_waitcnt vmcnt(4)" ::: "memory");
    __builtin_amdgcn_s_barrier();
    __builtin_amdgcn_sched_barrier(0);

    f32x4 S[4] = {};
    __builtin_amdgcn_s_setprio(1);
#pragma unroll
    for (int ks = 0; ks < 4; ++ks) {
#pragma unroll
      for (int mt = 0; mt < 4; ++mt) {
        bf16x8 kf;
        int slot = (ks * 4 + g) ^ (cq & 7);
        __builtin_memcpy(&kf, &Ks[(mt * 16 + cq) * 128 + slot * 8], 16);
        S[mt] = __builtin_amdgcn_mfma_f32_16x16x32_bf16(kf, qf[ks], S[mt], 0, 0, 0);
      }
    }
    __builtin_amdgcn_s_setprio(0);

    if (kt == sl) {  // causal mask, last tile only
#pragma unroll
      for (int mt = 0; mt < 4; ++mt)
#pragma unroll
        for (int i = 0; i < 4; ++i)
          if (kt * 64 + mt * 16 + g * 4 + i > qg) S[mt][i] = -1e30f;
    }
    float mx = S[0][0];
#pragma unroll
    for (int mt = 0; mt < 4; ++mt)
#pragma unroll
      for (int i = 0; i < 4; ++i) mx = fmaxf(mx, S[mt][i]);
    mx = fmaxf(mx, __shfl_xor(mx, 16));
    mx = fmaxf(mx, __shfl_xor(mx, 32));
    float mnew = fmaxf(mrow, mx);
    float al = __expf(mrow - mnew);
    mrow = mnew;
    float rs = 0.0f;
#pragma unroll
    for (int mt = 0; mt < 4; ++mt) {
      float e0 = __expf(S[mt][0] - mnew);
      float e1 = __expf(S[mt][1] - mnew);
      float e2 = __expf(S[mt][2] - mnew);
      float e3 = __expf(S[mt][3] - mnew);
      rs += (e0 + e1) + (e2 + e3);
      ushort4 pk;
      pk.x = f2b(e0); pk.y = f2b(e1); pk.z = f2b(e2); pk.w = f2b(e3);
      int colp = (((mt * 2 + (g >> 1)) ^ (cq & 7)) << 3) + (g & 1) * 4;
      *(ushort4*)&Ps[(w * 16 + cq) * 64 + colp] = pk;
    }
    rs += __shfl_xor(rs, 16);
    rs += __shfl_xor(rs, 32);
    lrow = lrow * al + rs;
#pragma unroll
    for (int dmt = 0; dmt < 8; ++dmt) {
      o[dmt][0] *= al; o[dmt][1] *= al;
      o[dmt][2] *= al; o[dmt][3] *= al;
    }

    // V fully landed before PV reads it
    asm volatile("s_waitcnt vmcnt(0)" ::: "memory");
    __builtin_amdgcn_s_barrier();
    __builtin_amdgcn_sched_barrier(0);

    __builtin_amdgcn_s_setprio(1);
#pragma unroll
    for (int ks = 0; ks < 2; ++ks) {
      bf16x8 pf;
      __builtin_memcpy(&pf, &Ps[(w * 16 + cq) * 64 + (((ks * 4 + g) ^ (cq & 7)) << 3)], 16);
#pragma unroll
      for (int dmt = 0; dmt < 8; ++dmt) {
        bf16x8 vf;
        int slot = (ks * 4 + g) ^ (cq & 7);
        __builtin_memcpy(&vf, &Vt[(dmt * 16 + cq) * 64 + slot * 8], 16);
        o[dmt] = __builtin_amdgcn_mfma_f32_16x16x32_bf16(vf, pf, o[dmt], 0, 0, 0);
      }
    }
    __builtin_amdgcn_s_setprio(0);
  }

  float inv = 1.0f / lrow;
  size_t base = ((size_t)(b * 2048 + qg)) * 2048 + h * 128;
#pragma unroll
  for (int dmt = 0; dmt < 8; ++dmt) {
    ushort4 t;
    t.x = f2b(o[dmt][0] * inv);
    t.y = f2b(o[dmt][1] * inv);
    t.z = f2b(o[dmt][2] * inv);
    t.w = f2b(o[dmt][3] * inv);
    *(ushort4*)(oh + base + dmt * 16 + g * 4) = t;
  }
}

extern "C" void kernel_launch(void* const* d_in, const int* in_sizes, int n_in,
                              void* d_out, int out_size, void* d_ws, size_t ws_size,
                              hipStream_t stream) {
  (void)in_sizes; (void)n_in; (void)out_size; (void)ws_size;
  const float* query = (const float*)d_in[0];
  const float* W_qkv = (const float*)d_in[1];
  const float* b_qkv = (const float*)d_in[2];
  const float* W_out = (const float*)d_in[3];
  const float* b_out = (const float*)d_in[4];
  float* out = (float*)d_out;
  char* ws = (char*)d_ws;

  u16*    Abf  = (u16*)(ws + 0);                    // 16 MB  query bf16
  u16*    W1bf = (u16*)(ws + (size_t)16777216);     // 24 MB  W_qkv bf16
  u16*    W2bf = (u16*)(ws + (size_t)41943040);     //  8 MB  W_out bf16
  u16*    qhp  = (u16*)(ws + (size_t)50331648);     // 16 MB  (B*H,L,128) pre-scaled
  u16*    khp  = (u16*)(ws + (size_t)67108864);     // 16 MB  (B*H,L,128)
  u16*    vhT  = (u16*)(ws + (size_t)83886080);     // 16 MB  (B*H,128,L)
  u16*    ohp  = (u16*)(ws + (size_t)100663296);    // 16 MB  attn out (B,L,2048)
  float2* tab  = (float2*)(ws + (size_t)117440512); //  1 MB  rope cos/sin

  convert_all<<<24576, 256, 0, stream>>>((const float4*)query, (const float4*)W_qkv,
                                         (const float4*)W_out, (ushort4*)ws, tab);
  gemm_qkv<<<dim3(48, 32), 256, 0, stream>>>(Abf, W1bf, b_qkv, tab, qhp, khp, vhT);
  attn_flash<<<dim3(1024), 256, 0, stream>>>(qhp, khp, vhT, ohp);
  gemm_bt<<<dim3(16, 32), 256, 0, stream>>>(ohp, W2bf, b_out, out, 4096, 2048, 2048);
}

// Round 7
// 364.341 us; speedup vs baseline: 1.0415x; 1.0415x over previous
//
#include <hip/hip_runtime.h>

typedef unsigned short u16;
typedef unsigned int u32;
typedef __bf16 bf16x8 __attribute__((ext_vector_type(8)));
typedef float f32x4 __attribute__((ext_vector_type(4)));

__device__ __forceinline__ u16 f2b(float f) {
  u32 u = __float_as_uint(f);
  u32 r = (u + 0x7fffu + ((u >> 16) & 1u)) >> 16;
  return (u16)r;
}
__device__ __forceinline__ float b2f(u16 v) {
  return __uint_as_float(((u32)v) << 16);
}

// ------- fused fp32 -> bf16 cast of query, W_qkv, W_out  (+ RoPE table) -------
__global__ __launch_bounds__(256) void convert_all(
    const float4* __restrict__ q, const float4* __restrict__ w1,
    const float4* __restrict__ w2, ushort4* __restrict__ out,
    float2* __restrict__ tab) {
  int i = blockIdx.x * 256 + threadIdx.x;  // < 6291456
  float4 f;
  if (i < 2097152) f = q[i];
  else if (i < 5242880) f = w1[i - 2097152];
  else f = w2[i - 5242880];
  ushort4 o;
  o.x = f2b(f.x); o.y = f2b(f.y); o.z = f2b(f.z); o.w = f2b(f.w);
  out[i] = o;
  // first 512 blocks also build the RoPE cos/sin table (131072 entries)
  if (blockIdx.x < 512) {
    int l = i >> 6, dp = i & 63;
    float inv = exp2f(-(float)dp * 0.20762050593046869f);  // log2(10000)/64
    float ang = (float)l * inv;
    float s, c;
    sincosf(ang, &s, &c);
    tab[i] = make_float2(c, s);
  }
}

// ---------------- GEMM1 + fused RoPE/head-split/V-transpose epilogue ----------
// Known-good structure (141 us, 730 TF): 128x128 tile, 4 blocks/CU TLP.
__global__ __launch_bounds__(256) void gemm_qkv(
    const u16* __restrict__ A, const u16* __restrict__ B,
    const float* __restrict__ bias, const float2* __restrict__ tab,
    u16* __restrict__ qh, u16* __restrict__ kh, u16* __restrict__ vhT) {
  __shared__ __align__(16) u16 sh[16512];  // As(8192) | Bs(8192); epi: T stride 129
  u16* As = sh;
  u16* Bs = sh + 8192;
  const int K = 2048;
  const int tid = threadIdx.x;
  const int lane = tid & 63;
  const int wave = tid >> 6;
  const int m0 = blockIdx.y * 128;
  const int n0 = blockIdx.x * 128;
  const int wm = (wave & 1) * 64;
  const int wn = (wave >> 1) * 64;
  f32x4 acc[4][4] = {};

  const int srow = wave * 32 + (lane >> 3);
  const int scb = ((lane & 7) ^ (lane >> 3)) * 16;
  const int fr = lane & 15;
  const int g = lane >> 4;

  for (int kt = 0; kt < 32; ++kt) {
    const int k0 = kt << 6;
    __syncthreads();
    {
      const char* gA = (const char*)A + ((size_t)(m0 + srow) * K + k0) * 2 + scb;
      const char* gB = (const char*)B + ((size_t)(n0 + srow) * K + k0) * 2 + scb;
#pragma unroll
      for (int i = 0; i < 4; ++i) {
        __builtin_amdgcn_global_load_lds(
            (__attribute__((address_space(1))) void*)(gA + (size_t)i * 8 * K * 2),
            (__attribute__((address_space(3))) void*)(As + (wave * 32 + i * 8) * 64),
            16, 0, 0);
        __builtin_amdgcn_global_load_lds(
            (__attribute__((address_space(1))) void*)(gB + (size_t)i * 8 * K * 2),
            (__attribute__((address_space(3))) void*)(Bs + (wave * 32 + i * 8) * 64),
            16, 0, 0);
      }
    }
    __syncthreads();
#pragma unroll
    for (int ks = 0; ks < 2; ++ks) {
      const int so = ((ks * 4 + g) ^ (fr & 7)) * 8;
      bf16x8 aF[4], bF[4];
#pragma unroll
      for (int mi = 0; mi < 4; ++mi)
        __builtin_memcpy(&aF[mi], &As[(wm + mi * 16 + fr) * 64 + so], 16);
#pragma unroll
      for (int ni = 0; ni < 4; ++ni)
        __builtin_memcpy(&bF[ni], &Bs[(wn + ni * 16 + fr) * 64 + so], 16);
#pragma unroll
      for (int mi = 0; mi < 4; ++mi)
#pragma unroll
        for (int ni = 0; ni < 4; ++ni)
          acc[mi][ni] = __builtin_amdgcn_mfma_f32_16x16x32_bf16(aF[mi], bF[ni], acc[mi][ni], 0, 0, 0);
    }
  }

  // ---- epilogue: acc -> LDS tile T (bf16, stride 129) ----
  __syncthreads();  // all waves done reading As/Bs before overwrite
  const int rq = (lane >> 4) * 4;
  const int cq = lane & 15;
#pragma unroll
  for (int mi = 0; mi < 4; ++mi) {
#pragma unroll
    for (int ni = 0; ni < 4; ++ni) {
      int c = wn + ni * 16 + cq;
      float bs = bias[n0 + c];
#pragma unroll
      for (int i = 0; i < 4; ++i) {
        int r = wm + mi * 16 + rq + i;
        sh[r * 129 + c] = f2b(acc[mi][ni][i] + bs);
      }
    }
  }
  __syncthreads();

  const int t = n0 >> 7;       // 0..47
  const int h = t & 15;
  const int bq = m0 >> 11;     // batch (M = B*L, 2048 each)
  const int l0 = m0 & 2047;
  const int bh = bq * 16 + h;

  if (t < 32) {
    // q or k head tile: RoPE rows. 128 rows x 64 pairs, 32 iters.
    const float qs = (t < 16) ? 0.08838834764831845f : 1.0f;
    u16* dst = (t < 16) ? qh : kh;
#pragma unroll 4
    for (int it = 0; it < 32; ++it) {
      int idx = it * 256 + tid;
      int l = idx >> 6, dp = idx & 63;
      float2 cs = tab[(size_t)(l0 + l) * 64 + dp];
      float x1 = b2f(sh[l * 129 + dp]);
      float x2 = b2f(sh[l * 129 + dp + 64]);
      size_t o = ((size_t)bh * 2048 + l0 + l) * 128;
      dst[o + dp]      = f2b((x1 * cs.x - x2 * cs.y) * qs);
      dst[o + dp + 64] = f2b((x2 * cs.x + x1 * cs.y) * qs);
    }
  } else {
    // v head tile: transposed store vhT[bh*128+d][l]. 128 d x 64 l-pairs.
#pragma unroll 4
    for (int it = 0; it < 32; ++it) {
      int idx = it * 256 + tid;
      int d = idx >> 6, l2 = (idx & 63) * 2;
      ushort2 t2;
      t2.x = sh[l2 * 129 + d];
      t2.y = sh[(l2 + 1) * 129 + d];
      *(ushort2*)(vhT + ((size_t)bh * 128 + d) * 2048 + l0 + l2) = t2;
    }
  }
}

// ---------------- GEMM2: out[M,N] = A[M,K] * B[N,K]^T + bias (fp32 out) -------
__global__ __launch_bounds__(256) void gemm_bt(
    const u16* __restrict__ A, const u16* __restrict__ B,
    const float* __restrict__ bias, float* __restrict__ C,
    int M, int N, int K) {
  __shared__ __align__(16) u16 As[128 * 64];
  __shared__ __align__(16) u16 Bs[128 * 64];
  const int tid = threadIdx.x;
  const int lane = tid & 63;
  const int wave = tid >> 6;
  const int m0 = blockIdx.y * 128;
  const int n0 = blockIdx.x * 128;
  const int wm = (wave & 1) * 64;
  const int wn = (wave >> 1) * 64;
  f32x4 acc[4][4] = {};

  const int srow = wave * 32 + (lane >> 3);
  const int scb = ((lane & 7) ^ (lane >> 3)) * 16;
  const int fr = lane & 15;
  const int g = lane >> 4;

  const int kiters = K >> 6;
  for (int kt = 0; kt < kiters; ++kt) {
    const int k0 = kt << 6;
    __syncthreads();
    {
      const char* gA = (const char*)A + ((size_t)(m0 + srow) * K + k0) * 2 + scb;
      const char* gB = (const char*)B + ((size_t)(n0 + srow) * K + k0) * 2 + scb;
#pragma unroll
      for (int i = 0; i < 4; ++i) {
        __builtin_amdgcn_global_load_lds(
            (__attribute__((address_space(1))) void*)(gA + (size_t)i * 8 * K * 2),
            (__attribute__((address_space(3))) void*)(As + (wave * 32 + i * 8) * 64),
            16, 0, 0);
        __builtin_amdgcn_global_load_lds(
            (__attribute__((address_space(1))) void*)(gB + (size_t)i * 8 * K * 2),
            (__attribute__((address_space(3))) void*)(Bs + (wave * 32 + i * 8) * 64),
            16, 0, 0);
      }
    }
    __syncthreads();
#pragma unroll
    for (int ks = 0; ks < 2; ++ks) {
      const int so = ((ks * 4 + g) ^ (fr & 7)) * 8;
      bf16x8 aF[4], bF[4];
#pragma unroll
      for (int mi = 0; mi < 4; ++mi)
        __builtin_memcpy(&aF[mi], &As[(wm + mi * 16 + fr) * 64 + so], 16);
#pragma unroll
      for (int ni = 0; ni < 4; ++ni)
        __builtin_memcpy(&bF[ni], &Bs[(wn + ni * 16 + fr) * 64 + so], 16);
#pragma unroll
      for (int mi = 0; mi < 4; ++mi)
#pragma unroll
        for (int ni = 0; ni < 4; ++ni)
          acc[mi][ni] = __builtin_amdgcn_mfma_f32_16x16x32_bf16(aF[mi], bF[ni], acc[mi][ni], 0, 0, 0);
    }
  }
  const int rq = (lane >> 4) * 4;
  const int cq = lane & 15;
#pragma unroll
  for (int mi = 0; mi < 4; ++mi) {
#pragma unroll
    for (int ni = 0; ni < 4; ++ni) {
      int col = n0 + wn + ni * 16 + cq;
      float bs = bias[col];
#pragma unroll
      for (int i = 0; i < 4; ++i) {
        int row = m0 + wm + mi * 16 + rq + i;
        C[(size_t)row * N + col] = acc[mi][ni][i] + bs;
      }
    }
  }
}

// ---------------- causal flash attention, S^T orientation ----------------
// One 64-row q-slice per block, grid 1024, 40 KB LDS -> 4 blocks/CU.
// head = bid&31 (bid%8 == head%8 -> head's K/V clustered on one XCD L2).
// sl from balanced groups {31-s, s, 23-s, 8+s}: any CU-aligned quadruple of
// blocks (bid, +256, +512, +768) sums to 66 tile-iters -> no straggler CU.
// K-latency fix (zero resource cost): K(t+1) DMA is issued right after the
// post-QK barrier (all waves done reading Ks) and lands during PV+stageV
// (~600+ cyc) -> next iter's vmcnt(4) is free. Cross-wave DMA visibility is
// always own-vmcnt-then-barrier. T13 defer-rescale: skip o-rescale and keep
// the old running max while tile max <= mrow+8 (P bounded by e^8, fine in
// bf16/f32). No setprio (suspected inter-block overlap suppressor at 4/CU).
__global__ __launch_bounds__(256, 4) void attn_flash(
    const u16* __restrict__ qh, const u16* __restrict__ kh,
    const u16* __restrict__ vhT, u16* __restrict__ oh) {
  __shared__ __align__(16) u16 Ks[64 * 128];   // 16 KB
  __shared__ __align__(16) u16 Vt[128 * 64];   // 16 KB
  __shared__ __align__(16) u16 Ps[64 * 64];    //  8 KB (chunk-swizzled)
  const int tid = threadIdx.x;
  const int lane = tid & 63;
  const int w = tid >> 6;
  const int cq = lane & 15;
  const int g = lane >> 4;
  const int bid = blockIdx.x;          // 0..1023
  const int bh = bid & 31;             // head; bh%8 == bid%8 (XCD cluster)
  const int r = bid >> 5;              // 0..31
  const int qq = r >> 3, s8 = r & 7;
  const int sl = (qq == 0) ? 31 - s8 : (qq == 1) ? s8 : (qq == 2) ? 23 - s8 : 8 + s8;
  const int b = bh >> 4, h = bh & 15;
  const int q0 = sl * 64;
  const int qg = q0 + w * 16 + cq;     // this lane's q row

  const int krl = lane >> 4;
  const int kcl = lane & 15;
  const int vrl = lane >> 3;
  const int vcl = lane & 7;

  auto stageK = [&](int kt) {
    const size_t kvb = (size_t)bh * 2048 + (size_t)kt * 64;
#pragma unroll
    for (int i = 0; i < 4; ++i) {
      int row = w * 16 + i * 4 + krl;
      int cgl = kcl ^ (row & 7);
      const char* src = (const char*)(kh + (kvb + row) * 128 + cgl * 8);
      __builtin_amdgcn_global_load_lds(
          (__attribute__((address_space(1))) void*)src,
          (__attribute__((address_space(3))) void*)(Ks + (w * 16 + i * 4) * 128),
          16, 0, 0);
    }
  };
  auto stageV = [&](int kt) {
#pragma unroll
    for (int i = 0; i < 4; ++i) {
      int row = w * 32 + i * 8 + vrl;
      int cgl = vcl ^ (row & 7);
      const char* src =
          (const char*)(vhT + ((size_t)bh * 128 + row) * 2048 + kt * 64 + cgl * 8);
      __builtin_amdgcn_global_load_lds(
          (__attribute__((address_space(1))) void*)src,
          (__attribute__((address_space(3))) void*)(Vt + (w * 32 + i * 8) * 64),
          16, 0, 0);
    }
  };

  // prologue: K(0) DMA first, then Q loads; drain K0 (oldest 4), Q drains at
  // the kt=0 mid-wait.
  stageK(0);
  __builtin_amdgcn_sched_barrier(0);
  bf16x8 qf[4];
  {
    const u16* qp = qh + ((size_t)bh * 2048 + qg) * 128 + g * 8;
#pragma unroll
    for (int ks = 0; ks < 4; ++ks)
      __builtin_memcpy(&qf[ks], qp + ks * 32, 16);
  }
  asm volatile("s_waitcnt vmcnt(4)" ::: "memory");

  f32x4 o[8] = {};
  float mrow = -1e30f, lrow = 0.0f;

  for (int kt = 0; kt <= sl; ++kt) {
    // top barrier: prev iter's Vt reads (PV) done before V overwrite
    __builtin_amdgcn_s_barrier();
    stageV(kt);
    // own K(kt) landed (issued an iter ago -> ~free); kt=0 also drains Q.
    // Newest 4 (V) stay in flight.
    asm volatile("s_waitcnt vmcnt(4)" ::: "memory");
    __builtin_amdgcn_s_barrier();  // all waves' K quarters landed

    f32x4 S[4] = {};
#pragma unroll
    for (int ks = 0; ks < 4; ++ks) {
#pragma unroll
      for (int mt = 0; mt < 4; ++mt) {
        bf16x8 kf;
        int slot = (ks * 4 + g) ^ (cq & 7);
        __builtin_memcpy(&kf, &Ks[(mt * 16 + cq) * 128 + slot * 8], 16);
        S[mt] = __builtin_amdgcn_mfma_f32_16x16x32_bf16(kf, qf[ks], S[mt], 0, 0, 0);
      }
    }

    if (kt == sl) {  // causal mask, last tile only
#pragma unroll
      for (int mt = 0; mt < 4; ++mt)
#pragma unroll
        for (int i = 0; i < 4; ++i)
          if (kt * 64 + mt * 16 + g * 4 + i > qg) S[mt][i] = -1e30f;
    }
    float mx = S[0][0];
#pragma unroll
    for (int mt = 0; mt < 4; ++mt)
#pragma unroll
      for (int i = 0; i < 4; ++i) mx = fmaxf(mx, S[mt][i]);
    mx = fmaxf(mx, __shfl_xor(mx, 16));
    mx = fmaxf(mx, __shfl_xor(mx, 32));
    // T13 defer-rescale: only advance the running max when it grows by >8.
    bool need = mx > mrow + 8.0f;
    float mnew = need ? mx : mrow;
    float al = need ? __expf(mrow - mnew) : 1.0f;
    mrow = mnew;
    float rs = 0.0f;
#pragma unroll
    for (int mt = 0; mt < 4; ++mt) {
      float e0 = __expf(S[mt][0] - mnew);
      float e1 = __expf(S[mt][1] - mnew);
      float e2 = __expf(S[mt][2] - mnew);
      float e3 = __expf(S[mt][3] - mnew);
      rs += (e0 + e1) + (e2 + e3);
      ushort4 pk;
      pk.x = f2b(e0); pk.y = f2b(e1); pk.z = f2b(e2); pk.w = f2b(e3);
      int colp = (((mt * 2 + (g >> 1)) ^ (cq & 7)) << 3) + (g & 1) * 4;
      *(ushort4*)&Ps[(w * 16 + cq) * 64 + colp] = pk;
    }
    rs += __shfl_xor(rs, 16);
    rs += __shfl_xor(rs, 32);
    lrow = lrow * al + rs;
    if (__any(need)) {
#pragma unroll
      for (int dmt = 0; dmt < 8; ++dmt) {
        o[dmt][0] *= al; o[dmt][1] *= al;
        o[dmt][2] *= al; o[dmt][3] *= al;
      }
    }

    // own V landed; barrier -> all waves' V landed AND all Ks reads done
    asm volatile("s_waitcnt vmcnt(0)" ::: "memory");
    __builtin_amdgcn_s_barrier();

    // K(t+1) prefetch: Ks is idle from here until next iter's QK; lands
    // during PV + next stageV (~600+ cyc) -> next vmcnt(4) is free.
    if (kt < sl) {
      stageK(kt + 1);
      __builtin_amdgcn_sched_barrier(0);
    }

#pragma unroll
    for (int ks = 0; ks < 2; ++ks) {
      bf16x8 pf;
      __builtin_memcpy(&pf, &Ps[(w * 16 + cq) * 64 + (((ks * 4 + g) ^ (cq & 7)) << 3)], 16);
#pragma unroll
      for (int dmt = 0; dmt < 8; ++dmt) {
        bf16x8 vf;
        int slot = (ks * 4 + g) ^ (cq & 7);
        __builtin_memcpy(&vf, &Vt[(dmt * 16 + cq) * 64 + slot * 8], 16);
        o[dmt] = __builtin_amdgcn_mfma_f32_16x16x32_bf16(vf, pf, o[dmt], 0, 0, 0);
      }
    }
  }

  float inv = 1.0f / lrow;
  size_t base = ((size_t)(b * 2048 + qg)) * 2048 + h * 128;
#pragma unroll
  for (int dmt = 0; dmt < 8; ++dmt) {
    ushort4 t;
    t.x = f2b(o[dmt][0] * inv);
    t.y = f2b(o[dmt][1] * inv);
    t.z = f2b(o[dmt][2] * inv);
    t.w = f2b(o[dmt][3] * inv);
    *(ushort4*)(oh + base + dmt * 16 + g * 4) = t;
  }
}

extern "C" void kernel_launch(void* const* d_in, const int* in_sizes, int n_in,
                              void* d_out, int out_size, void* d_ws, size_t ws_size,
                              hipStream_t stream) {
  (void)in_sizes; (void)n_in; (void)out_size; (void)ws_size;
  const float* query = (const float*)d_in[0];
  const float* W_qkv = (const float*)d_in[1];
  const float* b_qkv = (const float*)d_in[2];
  const float* W_out = (const float*)d_in[3];
  const float* b_out = (const float*)d_in[4];
  float* out = (float*)d_out;
  char* ws = (char*)d_ws;

  u16*    Abf  = (u16*)(ws + 0);                    // 16 MB  query bf16
  u16*    W1bf = (u16*)(ws + (size_t)16777216);     // 24 MB  W_qkv bf16
  u16*    W2bf = (u16*)(ws + (size_t)41943040);     //  8 MB  W_out bf16
  u16*    qhp  = (u16*)(ws + (size_t)50331648);     // 16 MB  (B*H,L,128) pre-scaled
  u16*    khp  = (u16*)(ws + (size_t)67108864);     // 16 MB  (B*H,L,128)
  u16*    vhT  = (u16*)(ws + (size_t)83886080);     // 16 MB  (B*H,128,L)
  u16*    ohp  = (u16*)(ws + (size_t)100663296);    // 16 MB  attn out (B,L,2048)
  float2* tab  = (float2*)(ws + (size_t)117440512); //  1 MB  rope cos/sin

  convert_all<<<24576, 256, 0, stream>>>((const float4*)query, (const float4*)W_qkv,
                                         (const float4*)W_out, (ushort4*)ws, tab);
  gemm_qkv<<<dim3(48, 32), 256, 0, stream>>>(Abf, W1bf, b_qkv, tab, qhp, khp, vhT);
  attn_flash<<<dim3(1024), 256, 0, stream>>>(qhp, khp, vhT, ohp);
  gemm_bt<<<dim3(16, 32), 256, 0, stream>>>(ohp, W2bf, b_out, out, 4096, 2048, 2048);
}